// Round 3
// baseline (792.485 us; speedup 1.0000x reference)
//
#include <hip/hip_runtime.h>

// ---------- types ----------
typedef _Float16 half8  __attribute__((ext_vector_type(8)));
typedef _Float16 half4v __attribute__((ext_vector_type(4)));
typedef float    float4v __attribute__((ext_vector_type(4)));

__device__ __forceinline__ float hsig(float x) {
  return fminf(fmaxf(fmaf(x, 0.2f, 0.5f), 0.0f), 1.0f);
}

// ---------- prep: A-pair build for x and h: d1 = f16(src); d2 = f16(src) with cols j<2048 negated ----------
__global__ __launch_bounds__(256) void cvt_pair(const float* __restrict__ x,
                                                const float* __restrict__ h,
                                                _Float16* __restrict__ d1x, _Float16* __restrict__ d2x,
                                                _Float16* __restrict__ d1h, _Float16* __restrict__ d2h) {
  const float* src = blockIdx.y ? h : x;
  _Float16* d1 = blockIdx.y ? d1h : d1x;
  _Float16* d2 = blockIdx.y ? d2h : d2x;
  int i = blockIdx.x * 256 + threadIdx.x;   // 1,048,576 float4 groups
  int base = i * 4;
  int j = base & 4095;
  float s = (j < 2048) ? -1.0f : 1.0f;
  float4 v = *(const float4*)&src[base];
  half4v h1 = {(_Float16)v.x, (_Float16)v.y, (_Float16)v.z, (_Float16)v.w};
  half4v h2 = {(_Float16)(s * v.x), (_Float16)(s * v.y), (_Float16)(s * v.z), (_Float16)(s * v.w)};
  *(half4v*)&d1[base] = h1;
  *(half4v*)&d2[base] = h2;
}

// ---------- prep: transpose+cast 4 weight matrices (2048 x 6144 f32) -> (6144 x 2048 f16) ----------
// Vectorized: float4 global loads, half8 global stores. tile[64][65]: both LDS phases
// are 2-way-aliased max (free). grid (32, 96, 4).
__global__ __launch_bounds__(256) void transpose_cast(
    const float* __restrict__ s0, const float* __restrict__ s1,
    const float* __restrict__ s2, const float* __restrict__ s3,
    _Float16* __restrict__ d0, _Float16* __restrict__ d1m,
    _Float16* __restrict__ d2m, _Float16* __restrict__ d3m)
{
  __shared__ float tile[64][65];
  const float* srcs[4] = {s0, s1, s2, s3};
  _Float16*    dsts[4] = {d0, d1m, d2m, d3m};
  const float* src = srcs[blockIdx.z];
  _Float16*    dst = dsts[blockIdx.z];

  const int tid = threadIdx.x;
  const int k0 = blockIdx.x * 64;   // 0..2047
  const int j0 = blockIdx.y * 64;   // 0..6143

  const int rr = tid >> 4;          // 0..15
  const int c4 = (tid & 15) * 4;    // 0..60
#pragma unroll
  for (int it = 0; it < 4; ++it) {
    int row = it * 16 + rr;
    float4 v = *(const float4*)&src[(size_t)(k0 + row) * 6144 + j0 + c4];
    tile[row][c4]     = v.x;
    tile[row][c4 + 1] = v.y;
    tile[row][c4 + 2] = v.z;
    tile[row][c4 + 3] = v.w;
  }
  __syncthreads();
  const int k8 = (tid & 7) * 8;     // 0..56
  const int jb = tid >> 3;          // 0..31
#pragma unroll
  for (int it = 0; it < 2; ++it) {
    int jl = it * 32 + jb;
    half8 hv;
#pragma unroll
    for (int i = 0; i < 8; ++i) hv[i] = (_Float16)tile[k8 + i][jl];
    *(half8*)&dst[(size_t)(j0 + jl) * 2048 + k0 + k8] = hv;
  }
}

// ---------- fused GEMM (R0's proven inner loop; occupancy-split scheduling) ----------
// MODE 0: grid (160, 8), 1280 uniform blocks of 64 iters, __launch_bounds__(256,5)
//   -> exactly 5 blocks/CU resident (LDS 5x32KB = 160KB, VGPR 68 <= 102).
//   bx < 128: heavy z/r tiles split by K-phase: part0 = X@K -> xacc (no bias),
//             part1 = H@R -> PH (no bias).  bx >= 128: light h tiles: X@K -> xacc + bias.
// MODE 1: (r*h)@Rh, grid (32, 8, 4): split-K=4 (K=1024 each, 16 iters) -> P0..P3.
template<int MODE>
__global__ __launch_bounds__(256, 5) void gemm_big(
    const _Float16* __restrict__ Ax1, const _Float16* __restrict__ Ax2,
    const _Float16* __restrict__ Ah1, const _Float16* __restrict__ Ah2,
    const _Float16* __restrict__ WKr, const _Float16* __restrict__ WKi,
    const _Float16* __restrict__ WRr, const _Float16* __restrict__ WRi,
    _Float16* __restrict__ xacc, _Float16* __restrict__ PH,
    _Float16* __restrict__ P0, _Float16* __restrict__ P1,
    _Float16* __restrict__ P2, _Float16* __restrict__ P3,
    const float* __restrict__ rbias, const float* __restrict__ ibias)
{
  __shared__ __align__(16) _Float16 lds[16384];   // 32 KB
  const int tid  = threadIdx.x;
  const int lane = tid & 63;
  const int wave = tid >> 6;
  const int quad = lane >> 4;
  const int r16  = lane & 15;
  const int wm = (wave >> 1) * 64;
  const int wn = (wave & 1) * 64;
  const int mbase = blockIdx.y * 128;

  constexpr int nit = MODE ? 16 : 32;
  constexpr int nph = MODE ? 1 : 2;

  const _Float16* pA[2];
  const _Float16* pB[2];
  _Float16* dst;
  int ldc;
  int n0;          // column base within dst
  bool wb;         // add bias in epilogue

  if (MODE == 0) {
    const int bx = blockIdx.x;
    bool useH;
    if (bx < 128) { n0 = (bx >> 1) * 128; useH = (bx & 1); }
    else          { n0 = 8192 + (bx - 128) * 128; useH = false; }
    const int  gate = n0 >> 12;
    const bool hi   = (n0 & 2048) != 0;
    const int  jp   = n0 & 2047;
    const size_t brow = (size_t)(gate * 2048 + jp) * 2048;
    const _Float16* Aa = useH ? (hi ? Ah2 : Ah1) : (hi ? Ax2 : Ax1);
    const _Float16* BL = useH ? (hi ? WRi : WRr) : (hi ? WKi : WKr);
    const _Float16* BH = useH ? (hi ? WRr : WRi) : (hi ? WKr : WKi);
    pA[0] = Aa + (size_t)mbase * 4096;  pB[0] = BL + brow;
    pA[1] = pA[0] + 2048;               pB[1] = BH + brow;
    if (useH) { dst = PH;   ldc = 8192;  }
    else      { dst = xacc; ldc = 12288; }
    wb = (bx >= 128);
  } else {
    n0 = blockIdx.x * 128;
    const bool hi = (n0 & 2048) != 0;
    const int  jp = n0 & 2047;
    const int z  = blockIdx.z;
    const int zz = z >> 1;              // K-half (which A sub-range / B matrix)
    const int koff = (z & 1) * 1024;    // quarter within the half
    const _Float16* Aa = hi ? Ax2 : Ax1;   // launch passes A1r/A2r here
    const _Float16* BL = hi ? WKi : WKr;   // launch passes Rh row bases in WK slots
    const _Float16* BH = hi ? WKr : WKi;
    pA[0] = Aa + (size_t)mbase * 4096 + zz * 2048 + koff;
    pB[0] = (zz ? BH : BL) + (size_t)jp * 2048 + koff;
    pA[1] = pA[0]; pB[1] = pB[0];
    dst = (z == 0) ? P0 : (z == 1) ? P1 : (z == 2) ? P2 : P3;
    ldc = 4096;
    wb = false;
  }

  float4v acc[4][4];
#pragma unroll
  for (int i = 0; i < 4; ++i)
#pragma unroll
    for (int j = 0; j < 4; ++j) acc[i][j] = (float4v){0.f, 0.f, 0.f, 0.f};

  // per-thread staging offsets (elements), loop-invariant.  BK=64: 8 granules/row.
  int offA[4], offB[4], ldsA[4], ldsB[4];
#pragma unroll
  for (int i = 0; i < 4; ++i) {
    int c = i * 256 + tid;          // granule chunk 0..1023
    int row = c >> 3;               // 0..127
    int sw = (c & 7) ^ (row & 7);   // XOR swizzle (verified conflict-free geometry)
    offA[i] = row * 4096 + sw * 8;  // A row stride 4096 elems
    offB[i] = row * 2048 + sw * 8;  // B row stride 2048 elems
    ldsA[i] = c * 8;
    ldsB[i] = 8192 + c * 8;
  }

#pragma unroll 1
  for (int p = 0; p < nph; ++p) {
    const _Float16* Ab = pA[p];
    const _Float16* Bb = pB[p];
#pragma unroll 1
    for (int it = 0; it < nit; ++it) {
#pragma unroll
      for (int i = 0; i < 4; ++i)
        __builtin_amdgcn_global_load_lds(
            (__attribute__((address_space(1))) void*)(Ab + offA[i]),
            (__attribute__((address_space(3))) void*)&lds[ldsA[i]], 16, 0, 0);
#pragma unroll
      for (int i = 0; i < 4; ++i)
        __builtin_amdgcn_global_load_lds(
            (__attribute__((address_space(1))) void*)(Bb + offB[i]),
            (__attribute__((address_space(3))) void*)&lds[ldsB[i]], 16, 0, 0);
      Ab += 64;
      Bb += 64;
      __syncthreads();
#pragma unroll
      for (int ks = 0; ks < 2; ++ks) {
        half8 af[4], bf[4];
        int akg = ks * 4 + quad;
#pragma unroll
        for (int t = 0; t < 4; ++t) {
          int arow = wm + t * 16 + r16;
          af[t] = *(const half8*)&lds[(arow * 8 + (akg ^ (arow & 7))) * 8];
          int brow = wn + t * 16 + r16;
          bf[t] = *(const half8*)&lds[8192 + (brow * 8 + (akg ^ (brow & 7))) * 8];
        }
#pragma unroll
        for (int mt = 0; mt < 4; ++mt)
#pragma unroll
          for (int nt = 0; nt < 4; ++nt)
            acc[mt][nt] = __builtin_amdgcn_mfma_f32_16x16x32_f16(af[mt], bf[nt], acc[mt][nt], 0, 0, 0);
      }
      __syncthreads();
    }
  }

  // epilogue: C/D layout col = lane&15, row = quad*4 + e
  const int mrow0 = mbase + wm + quad * 4;
  const int ncol0 = wn + r16;
#pragma unroll
  for (int nt = 0; nt < 4; ++nt) {
    int nl = ncol0 + nt * 16;
    float b = 0.0f;
    if (wb) {
      int n = n0 + nl;
      int g = n >> 12, j = n & 4095;
      b = (j < 2048) ? rbias[g * 2048 + j] : ibias[g * 2048 + j - 2048];
    }
#pragma unroll
    for (int mt = 0; mt < 4; ++mt)
#pragma unroll
      for (int e = 0; e < 4; ++e) {
        int m = mrow0 + mt * 16 + e;
        dst[(size_t)m * ldc + n0 + nl] = (_Float16)(acc[mt][nt][e] + b);
      }
  }
}

// ---------- rgate_fuse: reduce z (xacc += PH + bz, in place, pre-activation) and
//            build r*h panels: r = hsig(x_r + h@Rr + br); A1r = r*h; A2r = signed ----------
__global__ __launch_bounds__(256) void rgate_fuse(
    _Float16* __restrict__ xacc,
    const _Float16* __restrict__ PH,
    const float* __restrict__ h,
    const float* __restrict__ rb, const float* __restrict__ ib,
    _Float16* __restrict__ A1r, _Float16* __restrict__ A2r)
{
  int i = blockIdx.x * 256 + threadIdx.x;   // 1,048,576 groups (1024 rows x 1024)
  int m = i >> 10;
  int j = (i & 1023) * 4;                   // 0..4092
  float s = (j < 2048) ? -1.0f : 1.0f;

  // z gate: xacc_z = f16(x@Kz + h@Rz + bz)   (pre-activation; combine applies hsig)
  half4v xz = *(const half4v*)&xacc[(size_t)m * 12288 + j];
  half4v hz = *(const half4v*)&PH[(size_t)m * 8192 + j];
  float4 bz = *(const float4*)((j < 2048) ? &rb[j] : &ib[j - 2048]);
  half4v zo;
  zo[0] = (_Float16)((float)xz[0] + (float)hz[0] + bz.x);
  zo[1] = (_Float16)((float)xz[1] + (float)hz[1] + bz.y);
  zo[2] = (_Float16)((float)xz[2] + (float)hz[2] + bz.z);
  zo[3] = (_Float16)((float)xz[3] + (float)hz[3] + bz.w);
  *(half4v*)&xacc[(size_t)m * 12288 + j] = zo;

  // r gate + panels
  half4v xr = *(const half4v*)&xacc[(size_t)m * 12288 + 4096 + j];
  half4v hr = *(const half4v*)&PH[(size_t)m * 8192 + 4096 + j];
  float4 br = *(const float4*)((j < 2048) ? &rb[2048 + j] : &ib[2048 + j - 2048]);
  float4 hv = *(const float4*)&h[(size_t)m * 4096 + j];
  float p0 = hsig((float)xr[0] + (float)hr[0] + br.x) * hv.x;
  float p1 = hsig((float)xr[1] + (float)hr[1] + br.y) * hv.y;
  float p2 = hsig((float)xr[2] + (float)hr[2] + br.z) * hv.z;
  float p3 = hsig((float)xr[3] + (float)hr[3] + br.w) * hv.w;
  half4v o1 = {(_Float16)p0, (_Float16)p1, (_Float16)p2, (_Float16)p3};
  half4v o2 = {(_Float16)(s * p0), (_Float16)(s * p1), (_Float16)(s * p2), (_Float16)(s * p3)};
  size_t o = (size_t)m * 4096 + j;
  *(half4v*)&A1r[o] = o1;
  *(half4v*)&A2r[o] = o2;
}

// ---------- combine: out = z*h + (1-z)*tanh(xh + P0+P1+P2+P3) ----------
__global__ __launch_bounds__(256) void combine(const _Float16* __restrict__ xacc,
                                               const _Float16* __restrict__ P0,
                                               const _Float16* __restrict__ P1,
                                               const _Float16* __restrict__ P2,
                                               const _Float16* __restrict__ P3,
                                               const float* __restrict__ h,
                                               float* __restrict__ out) {
  int i = blockIdx.x * 256 + threadIdx.x;   // 1M float4 groups
  int base = i * 4;
  int m = base >> 12;
  int j = base & 4095;
  half4v zv = *(const half4v*)&xacc[(size_t)m * 12288 + j];          // pre-act (x+h+b)
  half4v xh = *(const half4v*)&xacc[(size_t)m * 12288 + 8192 + j];   // has bias
  half4v p0 = *(const half4v*)&P0[base];
  half4v p1 = *(const half4v*)&P1[base];
  half4v p2 = *(const half4v*)&P2[base];
  half4v p3 = *(const half4v*)&P3[base];
  float4 hv = *(const float4*)&h[base];
  float4 o;
#pragma unroll
  for (int e = 0; e < 4; ++e) {
    float z = hsig((float)zv[e]);
    float t = tanhf((float)xh[e] + (float)p0[e] + (float)p1[e] + (float)p2[e] + (float)p3[e]);
    float hval = (e == 0) ? hv.x : (e == 1) ? hv.y : (e == 2) ? hv.z : hv.w;
    float r = z * hval + (1.0f - z) * t;
    if (e == 0) o.x = r; else if (e == 1) o.y = r; else if (e == 2) o.z = r; else o.w = r;
  }
  *(float4*)&out[base] = o;
}

// ---------- launch ----------
extern "C" void kernel_launch(void* const* d_in, const int* in_sizes, int n_in,
                              void* d_out, int out_size, void* d_ws, size_t ws_size,
                              hipStream_t stream) {
  const float* inputs = (const float*)d_in[0];
  const float* h_tm1  = (const float*)d_in[1];
  const float* rk     = (const float*)d_in[2];
  const float* ik     = (const float*)d_in[3];
  const float* rrk    = (const float*)d_in[4];
  const float* irk    = (const float*)d_in[5];
  const float* rb     = (const float*)d_in[6];
  const float* ib     = (const float*)d_in[7];
  float* out = (float*)d_out;

  char* ws = (char*)d_ws;
  // ws layout (bytes), peak 176,160,768 (~168 MiB):
  _Float16* WrK  = (_Float16*)(ws + 0);           // 6144*2048*2 = 25,165,824 each
  _Float16* WiK  = (_Float16*)(ws + 25165824);
  _Float16* WrR  = (_Float16*)(ws + 50331648);
  _Float16* WiR  = (_Float16*)(ws + 75497472);
  _Float16* A1x  = (_Float16*)(ws + 100663296);   // 1024*4096*2 = 8,388,608 each
  _Float16* A2x  = (_Float16*)(ws + 109051904);
  _Float16* A1h  = (_Float16*)(ws + 117440512);
  _Float16* A2h  = (_Float16*)(ws + 125829120);
  _Float16* xacc = (_Float16*)(ws + 134217728);   // 1024*12288*2 = 25,165,824
  _Float16* PH   = (_Float16*)(ws + 159383552);   // 1024*8192*2  = 16,777,216
  // aliases (dead-data reuse):
  _Float16* A1r = A1x;                            // x-f16 panels dead after gemm0
  _Float16* A2r = A2x;
  _Float16* P0  = A1h;                            // h-f16 panels dead after gemm0
  _Float16* P1  = A2h;
  _Float16* P2  = (_Float16*)(ws + 0);            // K-weights dead after gemm0
  _Float16* P3  = (_Float16*)(ws + 8388608);

  cvt_pair<<<dim3(4096, 2), 256, 0, stream>>>(inputs, h_tm1, A1x, A2x, A1h, A2h);
  transpose_cast<<<dim3(32, 96, 4), 256, 0, stream>>>(rk, ik, rrk, irk, WrK, WiK, WrR, WiR);
  // main GEMM: 1280 uniform 64-iter blocks, 5 blocks/CU.
  //   heavy z/r: X@K -> xacc, H@R -> PH (no bias); light h: X@K + bias -> xacc.
  gemm_big<0><<<dim3(160, 8), 256, 0, stream>>>(A1x, A2x, A1h, A2h, WrK, WiK, WrR, WiR,
                                                xacc, PH, nullptr, nullptr, nullptr, nullptr,
                                                rb, ib);
  // z-reduce (in place) + r-gate panels
  rgate_fuse<<<4096, 256, 0, stream>>>(xacc, PH, h_tm1, rb, ib, A1r, A2r);
  // (r*h)@Rh, split-K=4 -> P0..P3
  gemm_big<1><<<dim3(32, 8, 4), 256, 0, stream>>>(A1r, A2r, nullptr, nullptr,
                                                  WrR + (size_t)4096 * 2048,
                                                  WiR + (size_t)4096 * 2048,
                                                  nullptr, nullptr, nullptr, nullptr,
                                                  P0, P1, P2, P3, nullptr, nullptr);
  // h = z*h_tm1 + (1-z)*tanh(x_h + sum(P))
  combine<<<4096, 256, 0, stream>>>(xacc, P0, P1, P2, P3, h_tm1, out);
}

// Round 4
// 490.989 us; speedup vs baseline: 1.6141x; 1.6141x over previous
//
#include <hip/hip_runtime.h>

// ---------- types ----------
typedef _Float16 half8  __attribute__((ext_vector_type(8)));
typedef _Float16 half4v __attribute__((ext_vector_type(4)));
typedef float    float4v __attribute__((ext_vector_type(4)));

__device__ __forceinline__ float hsig(float x) {
  return fminf(fmaxf(fmaf(x, 0.2f, 0.5f), 0.0f), 1.0f);
}

// ---------- prep: A-pair build for x and h: d1 = f16(src); d2 = f16(src) with cols j<2048 negated ----------
__global__ __launch_bounds__(256) void cvt_pair(const float* __restrict__ x,
                                                const float* __restrict__ h,
                                                _Float16* __restrict__ d1x, _Float16* __restrict__ d2x,
                                                _Float16* __restrict__ d1h, _Float16* __restrict__ d2h) {
  const float* src = blockIdx.y ? h : x;
  _Float16* d1 = blockIdx.y ? d1h : d1x;
  _Float16* d2 = blockIdx.y ? d2h : d2x;
  int i = blockIdx.x * 256 + threadIdx.x;   // 1,048,576 float4 groups
  int base = i * 4;
  int j = base & 4095;
  float s = (j < 2048) ? -1.0f : 1.0f;
  float4 v = *(const float4*)&src[base];
  half4v h1 = {(_Float16)v.x, (_Float16)v.y, (_Float16)v.z, (_Float16)v.w};
  half4v h2 = {(_Float16)(s * v.x), (_Float16)(s * v.y), (_Float16)(s * v.z), (_Float16)(s * v.w)};
  *(half4v*)&d1[base] = h1;
  *(half4v*)&d2[base] = h2;
}

// ---------- prep: transpose+cast 4 weight matrices (2048 x 6144 f32) -> (6144 x 2048 f16) ----------
// Vectorized (R3-proven correct): float4 global loads, half8 global stores.
__global__ __launch_bounds__(256) void transpose_cast(
    const float* __restrict__ s0, const float* __restrict__ s1,
    const float* __restrict__ s2, const float* __restrict__ s3,
    _Float16* __restrict__ d0, _Float16* __restrict__ d1m,
    _Float16* __restrict__ d2m, _Float16* __restrict__ d3m)
{
  __shared__ float tile[64][65];
  const float* srcs[4] = {s0, s1, s2, s3};
  _Float16*    dsts[4] = {d0, d1m, d2m, d3m};
  const float* src = srcs[blockIdx.z];
  _Float16*    dst = dsts[blockIdx.z];

  const int tid = threadIdx.x;
  const int k0 = blockIdx.x * 64;   // 0..2047
  const int j0 = blockIdx.y * 64;   // 0..6143

  const int rr = tid >> 4;          // 0..15
  const int c4 = (tid & 15) * 4;    // 0..60
#pragma unroll
  for (int it = 0; it < 4; ++it) {
    int row = it * 16 + rr;
    float4 v = *(const float4*)&src[(size_t)(k0 + row) * 6144 + j0 + c4];
    tile[row][c4]     = v.x;
    tile[row][c4 + 1] = v.y;
    tile[row][c4 + 2] = v.z;
    tile[row][c4 + 3] = v.w;
  }
  __syncthreads();
  const int k8 = (tid & 7) * 8;     // 0..56
  const int jb = tid >> 3;          // 0..31
#pragma unroll
  for (int it = 0; it < 2; ++it) {
    int jl = it * 32 + jb;
    half8 hv;
#pragma unroll
    for (int i = 0; i < 8; ++i) hv[i] = (_Float16)tile[k8 + i][jl];
    *(half8*)&dst[(size_t)(j0 + jl) * 2048 + k0 + k8] = hv;
  }
}

// ---------- fused GEMM: R0's proven structure, verbatim inner loop ----------
// FINAL=0: grid (96,8) = 768 blocks = exactly 3/CU. Heavy blocks (z,r gates):
//   K=8192 (X@K then H@R, 4 phases); light blocks (h gate): K=4096 (2 phases).
//   Load-balance remap: wgid -> (bx,by) via LUT so each CU triple is 2 heavy +
//   1 light under both depth-first and breadth-first CU fill; preserves
//   bx == wgid (mod 8) so B-panel-sharing blocks stay on one XCD.
//   Epilogue: z cols -> xacc+bias (pre-act); h cols -> xacc+bias;
//   r cols FUSED: p = hsig(acc+bias)*h_tm1 -> A1r (=p) / A2r (=signed p).
// FINAL=1: split-K over Rh: blockIdx.z selects K-half; writes f16 partial to
//   P[z][m*4096+n]. grid (32, 8, 2).
template<int FINAL>
__global__ __launch_bounds__(256, 3) void gemm_big(
    const _Float16* __restrict__ Ax1, const _Float16* __restrict__ Ax2,
    const _Float16* __restrict__ Ah1, const _Float16* __restrict__ Ah2,
    const _Float16* __restrict__ WKr, const _Float16* __restrict__ WKi,
    const _Float16* __restrict__ WRr, const _Float16* __restrict__ WRi,
    _Float16* __restrict__ xacc,
    _Float16* __restrict__ P0, _Float16* __restrict__ P1,
    const float* __restrict__ rbias, const float* __restrict__ ibias,
    const float* __restrict__ hfull,
    _Float16* __restrict__ A1r, _Float16* __restrict__ A2r)
{
  __shared__ __align__(16) _Float16 lds[16384];   // 32 KB
  const int tid  = threadIdx.x;
  const int lane = tid & 63;
  const int wave = tid >> 6;
  const int quad = lane >> 4;
  const int r16  = lane & 15;
  const int wm = (wave >> 1) * 64;
  const int wn = (wave & 1) * 64;

  int mbase, nbase;
  if (FINAL) {
    mbase = blockIdx.y * 128;
    nbase = blockIdx.x * 128;
  } else {
    // balance remap: lights (bxl 8..11) at LUT positions {2,4,7,9}
    const int wgid = blockIdx.y * 96 + blockIdx.x;
    const int xcd = wgid & 7;
    const int a   = wgid >> 3;          // 0..95
    const int by  = a / 12;
    const int p   = a - by * 12;        // 0..11
    const signed char LUT[12] = {0, 1, 8, 2, 9, 3, 4, 10, 5, 11, 6, 7};
    const int bxl = LUT[p];
    const int bx  = bxl * 8 + xcd;      // bijective; bx mod 8 == wgid mod 8
    mbase = by * 128;
    nbase = bx * 128;
  }

  const int  gate   = nbase >> 12;
  const bool hi     = (nbase & 2048) != 0;
  const int  jprime = nbase & 2047;

  int nph;
  const _Float16* pA[4];
  const _Float16* pB[4];
  if (FINAL) {
    nph = 1;
    const _Float16* Ax = hi ? Ax2 : Ax1;
    const _Float16* BL = hi ? WKi : WKr;   // caller passes Rh row bases in WK slots
    const _Float16* BH = hi ? WKr : WKi;
    if (blockIdx.z == 0) {
      pA[0] = Ax + (size_t)mbase * 4096;
      pB[0] = BL + (size_t)jprime * 2048;
    } else {
      pA[0] = Ax + (size_t)mbase * 4096 + 2048;
      pB[0] = BH + (size_t)jprime * 2048;
    }
  } else {
    const size_t browK = (size_t)(gate * 2048 + jprime) * 2048;
    const _Float16* Ax = hi ? Ax2 : Ax1;
    const _Float16* KL = hi ? WKi : WKr;
    const _Float16* KH = hi ? WKr : WKi;
    pA[0] = Ax + (size_t)mbase * 4096;      pB[0] = KL + browK;
    pA[1] = pA[0] + 2048;                   pB[1] = KH + browK;
    if (gate < 2) {
      nph = 4;
      const _Float16* Ah = hi ? Ah2 : Ah1;
      const _Float16* RL = hi ? WRi : WRr;
      const _Float16* RH = hi ? WRr : WRi;
      pA[2] = Ah + (size_t)mbase * 4096;    pB[2] = RL + browK;
      pA[3] = pA[2] + 2048;                 pB[3] = RH + browK;
    } else {
      nph = 2;
    }
  }

  float4v acc[4][4];
#pragma unroll
  for (int i = 0; i < 4; ++i)
#pragma unroll
    for (int j = 0; j < 4; ++j) acc[i][j] = (float4v){0.f, 0.f, 0.f, 0.f};

  // per-thread staging offsets (elements), loop-invariant.  BK=64: 8 granules/row.
  int offA[4], offB[4], ldsA[4], ldsB[4];
#pragma unroll
  for (int i = 0; i < 4; ++i) {
    int c = i * 256 + tid;          // granule chunk 0..1023
    int row = c >> 3;               // 0..127
    int sw = (c & 7) ^ (row & 7);   // XOR swizzle within row (R2 geometry, 0 conflicts)
    offA[i] = row * 4096 + sw * 8;  // A row stride 4096 elems
    offB[i] = row * 2048 + sw * 8;  // B row stride 2048 elems
    ldsA[i] = c * 8;
    ldsB[i] = 8192 + c * 8;
  }

#pragma unroll 1
  for (int p = 0; p < 4; ++p) {
    if (p >= nph) break;
    const _Float16* Ab = pA[p];
    const _Float16* Bb = pB[p];
#pragma unroll 1
    for (int it = 0; it < 32; ++it) {
#pragma unroll
      for (int i = 0; i < 4; ++i)
        __builtin_amdgcn_global_load_lds(
            (__attribute__((address_space(1))) void*)(Ab + offA[i]),
            (__attribute__((address_space(3))) void*)&lds[ldsA[i]], 16, 0, 0);
#pragma unroll
      for (int i = 0; i < 4; ++i)
        __builtin_amdgcn_global_load_lds(
            (__attribute__((address_space(1))) void*)(Bb + offB[i]),
            (__attribute__((address_space(3))) void*)&lds[ldsB[i]], 16, 0, 0);
      Ab += 64;
      Bb += 64;
      __syncthreads();
#pragma unroll
      for (int ks = 0; ks < 2; ++ks) {
        half8 af[4], bf[4];
        int akg = ks * 4 + quad;
#pragma unroll
        for (int t = 0; t < 4; ++t) {
          int arow = wm + t * 16 + r16;
          af[t] = *(const half8*)&lds[(arow * 8 + (akg ^ (arow & 7))) * 8];
          int brow = wn + t * 16 + r16;
          bf[t] = *(const half8*)&lds[8192 + (brow * 8 + (akg ^ (brow & 7))) * 8];
        }
#pragma unroll
        for (int mt = 0; mt < 4; ++mt)
#pragma unroll
          for (int nt = 0; nt < 4; ++nt)
            acc[mt][nt] = __builtin_amdgcn_mfma_f32_16x16x32_f16(af[mt], bf[nt], acc[mt][nt], 0, 0, 0);
      }
      __syncthreads();
    }
  }

  // epilogue: C/D layout col = lane&15, row = quad*4 + e
  const int mrow0 = mbase + wm + quad * 4;
  const int ncol0 = nbase + wn + r16;
  if (!FINAL) {
    if (gate == 1) {
      // r columns: fused rgate. p = hsig(acc + br) * h ; A1r = p ; A2r = signed p
#pragma unroll
      for (int nt = 0; nt < 4; ++nt) {
        int n = ncol0 + nt * 16;
        int j = n & 4095;                       // 0..4095 within gate
        float b = (j < 2048) ? rbias[2048 + j] : ibias[j];
        float s = (j < 2048) ? -1.0f : 1.0f;
#pragma unroll
        for (int mt = 0; mt < 4; ++mt)
#pragma unroll
          for (int e = 0; e < 4; ++e) {
            int m = mrow0 + mt * 16 + e;
            float pv = hsig(acc[mt][nt][e] + b) * hfull[(size_t)m * 4096 + j];
            A1r[(size_t)m * 4096 + j] = (_Float16)pv;
            A2r[(size_t)m * 4096 + j] = (_Float16)(s * pv);
          }
      }
    } else {
#pragma unroll
      for (int nt = 0; nt < 4; ++nt) {
        int n = ncol0 + nt * 16;
        int g = n >> 12, j = n & 4095;
        float b = (j < 2048) ? rbias[g * 2048 + j] : ibias[g * 2048 + j - 2048];
#pragma unroll
        for (int mt = 0; mt < 4; ++mt)
#pragma unroll
          for (int e = 0; e < 4; ++e) {
            int m = mrow0 + mt * 16 + e;
            xacc[(size_t)m * 12288 + n] = (_Float16)(acc[mt][nt][e] + b);
          }
      }
    }
  } else {
    _Float16* P = blockIdx.z ? P1 : P0;
#pragma unroll
    for (int nt = 0; nt < 4; ++nt) {
      int n = ncol0 + nt * 16;
#pragma unroll
      for (int mt = 0; mt < 4; ++mt)
#pragma unroll
        for (int e = 0; e < 4; ++e) {
          int m = mrow0 + mt * 16 + e;
          P[(size_t)m * 4096 + n] = (_Float16)acc[mt][nt][e];
        }
    }
  }
}

// ---------- combine: out = z*h + (1-z)*tanh(xh + P0 + P1) ----------
__global__ __launch_bounds__(256) void combine(const _Float16* __restrict__ xacc,
                                               const _Float16* __restrict__ P0,
                                               const _Float16* __restrict__ P1,
                                               const float* __restrict__ h,
                                               float* __restrict__ out) {
  int i = blockIdx.x * 256 + threadIdx.x;   // 1M float4 groups
  int base = i * 4;
  int m = base >> 12;
  int j = base & 4095;
  half4v zv = *(const half4v*)&xacc[(size_t)m * 12288 + j];          // pre-act z (has bias)
  half4v xh = *(const half4v*)&xacc[(size_t)m * 12288 + 8192 + j];   // has bias
  half4v p0 = *(const half4v*)&P0[base];
  half4v p1 = *(const half4v*)&P1[base];
  float4 hv = *(const float4*)&h[base];
  float4 o;
  {
    float z = hsig((float)zv[0]); float t = tanhf((float)xh[0] + (float)p0[0] + (float)p1[0]);
    o.x = z * hv.x + (1.0f - z) * t;
  }
  {
    float z = hsig((float)zv[1]); float t = tanhf((float)xh[1] + (float)p0[1] + (float)p1[1]);
    o.y = z * hv.y + (1.0f - z) * t;
  }
  {
    float z = hsig((float)zv[2]); float t = tanhf((float)xh[2] + (float)p0[2] + (float)p1[2]);
    o.z = z * hv.z + (1.0f - z) * t;
  }
  {
    float z = hsig((float)zv[3]); float t = tanhf((float)xh[3] + (float)p0[3] + (float)p1[3]);
    o.w = z * hv.w + (1.0f - z) * t;
  }
  *(float4*)&out[base] = o;
}

// ---------- launch ----------
extern "C" void kernel_launch(void* const* d_in, const int* in_sizes, int n_in,
                              void* d_out, int out_size, void* d_ws, size_t ws_size,
                              hipStream_t stream) {
  const float* inputs = (const float*)d_in[0];
  const float* h_tm1  = (const float*)d_in[1];
  const float* rk     = (const float*)d_in[2];
  const float* ik     = (const float*)d_in[3];
  const float* rrk    = (const float*)d_in[4];
  const float* irk    = (const float*)d_in[5];
  const float* rb     = (const float*)d_in[6];
  const float* ib     = (const float*)d_in[7];
  float* out = (float*)d_out;

  char* ws = (char*)d_ws;
  // ws layout (bytes), peak 176,160,768 (~168 MiB):
  _Float16* WrK  = (_Float16*)(ws + 0);           // 6144*2048*2 = 25,165,824 each
  _Float16* WiK  = (_Float16*)(ws + 25165824);
  _Float16* WrR  = (_Float16*)(ws + 50331648);
  _Float16* WiR  = (_Float16*)(ws + 75497472);
  _Float16* A1x  = (_Float16*)(ws + 100663296);   // 1024*4096*2 = 8,388,608 each
  _Float16* A2x  = (_Float16*)(ws + 109051904);
  _Float16* A1h  = (_Float16*)(ws + 117440512);
  _Float16* A2h  = (_Float16*)(ws + 125829120);
  _Float16* xacc = (_Float16*)(ws + 134217728);   // 1024*12288*2 = 25,165,824
  _Float16* A1r  = (_Float16*)(ws + 159383552);   // dedicated (written by gemm0 epilogue)
  _Float16* A2r  = (_Float16*)(ws + 167772160);
  // aliases (dead-data reuse):
  _Float16* P0   = A1h;   // h-f16 panels dead after gemm0
  _Float16* P1   = A2h;

  cvt_pair<<<dim3(4096, 2), 256, 0, stream>>>(inputs, h_tm1, A1x, A2x, A1h, A2h);
  transpose_cast<<<dim3(32, 96, 4), 256, 0, stream>>>(rk, ik, rrk, irk, WrK, WiK, WrR, WiR);
  // fused: z -> xacc (pre-act+bias), h -> xacc (+bias), r -> A1r/A2r (fused rgate)
  gemm_big<0><<<dim3(96, 8), 256, 0, stream>>>(A1x, A2x, A1h, A2h, WrK, WiK, WrR, WiR,
                                               xacc, nullptr, nullptr, rb, ib,
                                               h_tm1, A1r, A2r);
  // split-K partials of (r*h) @ Rh  (N = 4096, K halves -> P0/P1)
  gemm_big<1><<<dim3(32, 8, 2), 256, 0, stream>>>(A1r, A2r, nullptr, nullptr,
                                                  WrR + (size_t)4096 * 2048,
                                                  WiR + (size_t)4096 * 2048,
                                                  nullptr, nullptr, nullptr, P0, P1,
                                                  nullptr, nullptr, nullptr, nullptr, nullptr);
  // h = z*h_tm1 + (1-z)*tanh(x_h + P0 + P1)
  combine<<<4096, 256, 0, stream>>>(xacc, P0, P1, h_tm1, out);
}